// Round 5
// baseline (316.179 us; speedup 1.0000x reference)
//
#include <hip/hip_runtime.h>

using half8 = __attribute__((ext_vector_type(8))) _Float16;
using f32x4 = __attribute__((ext_vector_type(4))) float;

typedef __attribute__((address_space(3))) unsigned int lds_uint;
typedef __attribute__((address_space(1))) const unsigned int glb_uint;
__device__ __forceinline__ void async_copy16(const void* g, void* l) {
  __builtin_amdgcn_global_load_lds((glb_uint*)g, (lds_uint*)l, 16, 0, 0);
}

// ---------------- fast zero (replaces pathological graph-captured hipMemsetAsync) ----
__global__ void zero_kernel(int4* __restrict__ p, int n4) {
  int i = blockIdx.x * 256 + threadIdx.x;
  if (i < n4) p[i] = make_int4(0, 0, 0, 0);
}

// ---------------- prep: all 4 layers' weights -> fp16, one kernel ----------------
// w1 [128][768]; w2 [64][64]; w3 [32][32]; w4 [16][32] (k-padded 16->32, col-padded 10->16)
__global__ void prep_all_kernel(const float* __restrict__ W1l, const float* __restrict__ W1r,
                                const float* __restrict__ W2l, const float* __restrict__ W2r,
                                const float* __restrict__ W3l, const float* __restrict__ W3r,
                                const float* __restrict__ W4l, const float* __restrict__ W4r,
                                _Float16* __restrict__ w1, _Float16* __restrict__ w2,
                                _Float16* __restrict__ w3, _Float16* __restrict__ w4) {
  int i = blockIdx.x * 256 + threadIdx.x;
  if (i < 98304) {  // 128*768
    int c = i / 768, k = i - c * 768;
    float v = (c < 64) ? W1l[k * 64 + c] : W1r[k * 64 + (c - 64)];
    w1[i] = (_Float16)v;
  } else if (i < 98304 + 4096) {  // w2: [64][64]
    int j = i - 98304;
    int c = j >> 6, k = j & 63;
    float v = (c < 32) ? W2l[k * 32 + c] : W2r[k * 32 + (c - 32)];
    w2[j] = (_Float16)v;
  } else if (i < 98304 + 4096 + 1024) {  // w3: [32][32]
    int j = i - (98304 + 4096);
    int c = j >> 5, k = j & 31;
    float v = (c < 16) ? W3l[k * 16 + c] : W3r[k * 16 + (c - 16)];
    w3[j] = (_Float16)v;
  } else if (i < 98304 + 4096 + 1024 + 512) {  // w4: [16][32], k<16 real, c<10 real
    int j = i - (98304 + 4096 + 1024);
    int c = j >> 5, k = j & 31;
    float v = 0.f;
    if (k < 16) {
      if (c < 5) v = W4l[k * 5 + c];
      else if (c < 10) v = W4r[k * 5 + (c - 5)];
    }
    w4[j] = (_Float16)v;
  }
}

// ---------------- CSR build ----------------
__global__ void deg_kernel(const int* __restrict__ dst, int* __restrict__ cnt, int e) {
  int i = blockIdx.x * 256 + threadIdx.x;
  if (i < e) atomicAdd(&cnt[dst[i]], 1);
}

// exclusive scan pass 1 (+ inv_deg fused)
__global__ void scan1_kernel(const int* __restrict__ cnt, int* __restrict__ off,
                             int* __restrict__ bsum, float* __restrict__ invd, int nodes) {
  __shared__ int sh[256];
  int tid = threadIdx.x;
  int base = blockIdx.x * 1024 + tid * 4;
  int a0 = (base + 0 < nodes) ? cnt[base + 0] : 0;
  int a1 = (base + 1 < nodes) ? cnt[base + 1] : 0;
  int a2 = (base + 2 < nodes) ? cnt[base + 2] : 0;
  int a3 = (base + 3 < nodes) ? cnt[base + 3] : 0;
  if (base + 0 < nodes) invd[base + 0] = a0 > 0 ? 1.0f / (float)a0 : 0.f;
  if (base + 1 < nodes) invd[base + 1] = a1 > 0 ? 1.0f / (float)a1 : 0.f;
  if (base + 2 < nodes) invd[base + 2] = a2 > 0 ? 1.0f / (float)a2 : 0.f;
  if (base + 3 < nodes) invd[base + 3] = a3 > 0 ? 1.0f / (float)a3 : 0.f;
  int s3 = a0 + a1 + a2 + a3;
  sh[tid] = s3;
  __syncthreads();
  for (int d = 1; d < 256; d <<= 1) {
    int v = (tid >= d) ? sh[tid - d] : 0;
    __syncthreads();
    sh[tid] += v;
    __syncthreads();
  }
  int excl = sh[tid] - s3;
  if (base + 0 <= nodes) off[base + 0] = excl;
  if (base + 1 <= nodes) off[base + 1] = excl + a0;
  if (base + 2 <= nodes) off[base + 2] = excl + a0 + a1;
  if (base + 3 <= nodes) off[base + 3] = excl + a0 + a1 + a2;
  if (tid == 255) bsum[blockIdx.x] = sh[255];
}

__global__ void scan2_kernel(int* __restrict__ bsum, int nb) {
  __shared__ int sh[128];
  int tid = threadIdx.x;
  int v = (tid < nb) ? bsum[tid] : 0;
  sh[tid] = v;
  __syncthreads();
  for (int d = 1; d < 128; d <<= 1) {
    int u = (tid >= d) ? sh[tid - d] : 0;
    __syncthreads();
    sh[tid] += u;
    __syncthreads();
  }
  if (tid < nb) bsum[tid] = sh[tid] - v;
}

__global__ void scan3_kernel(int* __restrict__ off, const int* __restrict__ bsum, int ntot) {
  int i = blockIdx.x * 256 + threadIdx.x;
  if (i < ntot) off[i] += bsum[i >> 10];
}

__global__ void sortfill_kernel(const int* __restrict__ src, const int* __restrict__ dst,
                                const int* __restrict__ off, int* __restrict__ cur,
                                int* __restrict__ csr, int e) {
  int i = blockIdx.x * 256 + threadIdx.x;
  if (i < e) {
    int d = dst[i];
    int pos = atomicAdd(&cur[d], 1);
    csr[off[d] + pos] = src[i];
  }
}

// ---------------- layer-1 MFMA GEMM with global_load_lds staging ----------------
// Block: 256 thr (4 waves), tile 128 rows x 128 cols, BK=64 fp32, LDS 2x32KB dbuf.
// XOR swizzle: LDS[r][byte] = x[r][byte ^ ((r&7)<<4)]  (applied on global source).
__global__ __launch_bounds__(256, 2) void gemm1_kernel(
    const float* __restrict__ x,       // [n][768]
    const _Float16* __restrict__ w16,  // [128][768]
    const float* __restrict__ bias,    // [64]
    _Float16* __restrict__ p, _Float16* __restrict__ q, int n) {
  constexpr int DI = 768, BK = 64, NT = DI / BK;
  __shared__ float xs[2][128 * BK];  // 2 x 32 KB
  int t = threadIdx.x;
  int lane = t & 63, w = t >> 6;
  int lm = lane & 15, lk = lane >> 4;
  int m0 = blockIdx.x * 128;

  // staging: thread covers 8 x 16B; wave chunk j at lds float off (j*4+w)*256
  const float* gp[8];
  int jbase[8];
#pragma unroll
  for (int j = 0; j < 8; ++j) {
    int row = (j * 4 + w) * 4 + (lane >> 4);
    int g = (lane & 15) ^ (row & 7);  // 16B-granule index after inverse swizzle
    int grow = m0 + row;
    if (grow >= n) grow = n - 1;
    gp[j] = x + (size_t)grow * DI + g * 4;
    jbase[j] = (j * 4 + w) * 256;
  }

  f32x4 acc[2][8];
#pragma unroll
  for (int mi = 0; mi < 2; ++mi)
#pragma unroll
    for (int ni = 0; ni < 8; ++ni) acc[mi][ni] = (f32x4){0.f, 0.f, 0.f, 0.f};

  // prologue: stage tile 0
#pragma unroll
  for (int j = 0; j < 8; ++j) async_copy16(gp[j], &xs[0][jbase[j]]);
  asm volatile("s_waitcnt vmcnt(0)" ::: "memory");
  __syncthreads();

  int r0l = w * 32 + lm, r1l = r0l + 16;
  const _Float16* wp = w16 + (size_t)lm * DI + lk * 8;

  for (int ts = 0; ts < NT; ++ts) {
    int cur = ts & 1;
    if (ts + 1 < NT) {
      int kc = (ts + 1) * BK;
#pragma unroll
      for (int j = 0; j < 8; ++j) async_copy16(gp[j] + kc, &xs[cur ^ 1][jbase[j]]);
    }
    const float* xb = xs[cur];
    int kc0 = ts * BK;
#pragma unroll
    for (int s = 0; s < 2; ++s) {
      // swizzled fragment reads: float off = r*64 + (((s*8+lk*2+h) ^ (r&7)) << 2)
      f32x4 v0a = *(const f32x4*)(xb + r0l * 64 + ((((s << 3) + (lk << 1) + 0) ^ (r0l & 7)) << 2));
      f32x4 v0b = *(const f32x4*)(xb + r0l * 64 + ((((s << 3) + (lk << 1) + 1) ^ (r0l & 7)) << 2));
      f32x4 v1a = *(const f32x4*)(xb + r1l * 64 + ((((s << 3) + (lk << 1) + 0) ^ (r1l & 7)) << 2));
      f32x4 v1b = *(const f32x4*)(xb + r1l * 64 + ((((s << 3) + (lk << 1) + 1) ^ (r1l & 7)) << 2));
      half8 a0, a1;
#pragma unroll
      for (int j = 0; j < 4; ++j) {
        a0[j] = (_Float16)v0a[j]; a0[4 + j] = (_Float16)v0b[j];
        a1[j] = (_Float16)v1a[j]; a1[4 + j] = (_Float16)v1b[j];
      }
#pragma unroll
      for (int ni = 0; ni < 8; ++ni) {
        half8 b = *(const half8*)(wp + (size_t)ni * 16 * DI + kc0 + s * 32);
        acc[0][ni] = __builtin_amdgcn_mfma_f32_16x16x32_f16(a0, b, acc[0][ni], 0, 0, 0);
        acc[1][ni] = __builtin_amdgcn_mfma_f32_16x16x32_f16(a1, b, acc[1][ni], 0, 0, 0);
      }
    }
    asm volatile("s_waitcnt vmcnt(0)" ::: "memory");
    __syncthreads();
  }

  // C/D: col = ni*16 + lm, row = m0 + w*32 + mi*16 + lk*4 + j
#pragma unroll
  for (int mi = 0; mi < 2; ++mi)
#pragma unroll
    for (int ni = 0; ni < 8; ++ni) {
      int col = ni * 16 + lm;
#pragma unroll
      for (int j = 0; j < 4; ++j) {
        int row = m0 + w * 32 + mi * 16 + lk * 4 + j;
        if (row < n) {
          float v = acc[mi][ni][j];
          if (col < 64) p[(size_t)row * 64 + col] = (_Float16)v;
          else q[(size_t)row * 64 + (col - 64)] = (_Float16)(v + bias[col - 64]);
        }
      }
    }
}

// ---------------- fused aggregate(+relu) -> gemm for layers 2-4 ----------------
// Phase A: 2 threads/node aggregate h=relu(mean(pin[src])+qin) into LDS [128][SP].
// Phase B: 4 waves x 32 rows x NC cols MFMA from LDS, write pout/qout fp16.
template <int DIR, int DIP, int PSI, int NC, int NCR, int DO, int PSO>
__global__ __launch_bounds__(256) void fused_agg_gemm_kernel(
    const _Float16* __restrict__ pin, const _Float16* __restrict__ qin,
    const int* __restrict__ off, const int* __restrict__ csr, const float* __restrict__ invd,
    const _Float16* __restrict__ w16, const float* __restrict__ bias,
    _Float16* __restrict__ pout, _Float16* __restrict__ qout, int n) {
  constexpr int SP = DIP + 8;   // LDS row stride (fp16): bank-staggered
  constexpr int C8 = DIR / 8;   // real half8 chunks per node
  constexpr int CT = C8 / 2;    // chunks per thread (2 threads/node)
  constexpr int NF = NC / 16;
  __shared__ _Float16 hs[128 * SP];
  int t = threadIdx.x;
  int node_l = t >> 1, half = t & 1;
  int node = blockIdx.x * 128 + node_l;

  if (node < n) {
    int e0 = off[node], e1 = off[node + 1];
    const half8* p8 = (const half8*)pin;
    float s[CT][8];
#pragma unroll
    for (int c = 0; c < CT; ++c)
#pragma unroll
      for (int j = 0; j < 8; ++j) s[c][j] = 0.f;
    for (int e = e0; e < e1; ++e) {
      int src = csr[e];
#pragma unroll
      for (int c = 0; c < CT; ++c) {
        half8 v = p8[(size_t)src * PSI + half * CT + c];
#pragma unroll
        for (int j = 0; j < 8; ++j) s[c][j] += (float)v[j];
      }
    }
    float id = invd[node];
#pragma unroll
    for (int c = 0; c < CT; ++c) {
      half8 qv = ((const half8*)qin)[(size_t)node * PSI + half * CT + c];
      half8 o;
#pragma unroll
      for (int j = 0; j < 8; ++j) o[j] = (_Float16)fmaxf(s[c][j] * id + (float)qv[j], 0.f);
      *(half8*)(hs + node_l * SP + (half * CT + c) * 8) = o;
    }
    if (DIP > DIR) {  // zero-pad k (layer 4)
      half8 z = {};
      *(half8*)(hs + node_l * SP + (C8 + half) * 8) = z;
    }
  }
  __syncthreads();

  // Phase B
  int lane = t & 63, w = t >> 6;
  int lm = lane & 15, lk = lane >> 4;
  int r0l = w * 32 + lm, r1l = r0l + 16;
  const _Float16* wp = w16 + (size_t)lm * DIP + lk * 8;
  f32x4 acc[2][NF];
#pragma unroll
  for (int mi = 0; mi < 2; ++mi)
#pragma unroll
    for (int ni = 0; ni < NF; ++ni) acc[mi][ni] = (f32x4){0.f, 0.f, 0.f, 0.f};
#pragma unroll
  for (int kc = 0; kc < DIP; kc += 32) {
    half8 a0 = *(const half8*)(hs + r0l * SP + kc + lk * 8);
    half8 a1 = *(const half8*)(hs + r1l * SP + kc + lk * 8);
#pragma unroll
    for (int ni = 0; ni < NF; ++ni) {
      half8 b = *(const half8*)(wp + (size_t)ni * 16 * DIP + kc);
      acc[0][ni] = __builtin_amdgcn_mfma_f32_16x16x32_f16(a0, b, acc[0][ni], 0, 0, 0);
      acc[1][ni] = __builtin_amdgcn_mfma_f32_16x16x32_f16(a1, b, acc[1][ni], 0, 0, 0);
    }
  }
#pragma unroll
  for (int mi = 0; mi < 2; ++mi)
#pragma unroll
    for (int ni = 0; ni < NF; ++ni) {
      int col = ni * 16 + lm;
      if (col >= NCR) continue;
#pragma unroll
      for (int j = 0; j < 4; ++j) {
        int row = blockIdx.x * 128 + w * 32 + mi * 16 + lk * 4 + j;
        if (row < n) {
          float v = acc[mi][ni][j];
          if (col < DO) pout[(size_t)row * PSO + col] = (_Float16)v;
          else qout[(size_t)row * PSO + (col - DO)] = (_Float16)(v + bias[col - DO]);
        }
      }
    }
}

// final aggregation: p,q fp16 [n][8] (cols 0-4 valid), out fp32 [n][5]
__global__ __launch_bounds__(256) void aggregate_last_kernel(
    const _Float16* __restrict__ p, const _Float16* __restrict__ q,
    const int* __restrict__ off, const int* __restrict__ csr,
    const float* __restrict__ invd, float* __restrict__ out, int n) {
  int t = blockIdx.x * 256 + threadIdx.x;
  int node = t >> 3;
  int c = t & 7;
  if (node >= n || c >= 5) return;
  int e0 = off[node], e1 = off[node + 1];
  float s = 0.f;
  for (int e = e0; e < e1; ++e) s += (float)p[(size_t)csr[e] * 8 + c];
  out[(size_t)node * 5 + c] = s * invd[node] + (float)q[(size_t)node * 8 + c];
}

// ---------------- launch ----------------
extern "C" void kernel_launch(void* const* d_in, const int* in_sizes, int n_in,
                              void* d_out, int out_size, void* d_ws, size_t ws_size,
                              hipStream_t stream) {
  const float* x = (const float*)d_in[0];
  const int* ei = (const int*)d_in[1];
  const int E = in_sizes[1] / 2;
  const int* esrc = ei;
  const int* edst = ei + E;
  const float* W1l = (const float*)d_in[3];
  const float* W1r = (const float*)d_in[4];
  const float* b1 = (const float*)d_in[5];
  const float* W2l = (const float*)d_in[6];
  const float* W2r = (const float*)d_in[7];
  const float* b2 = (const float*)d_in[8];
  const float* W3l = (const float*)d_in[9];
  const float* W3r = (const float*)d_in[10];
  const float* b3 = (const float*)d_in[11];
  const float* W4l = (const float*)d_in[12];
  const float* W4r = (const float*)d_in[13];
  const float* b4 = (const float*)d_in[14];
  const int N = in_sizes[0] / 768;
  float* out = (float*)d_out;
  (void)n_in; (void)out_size; (void)ws_size;

  char* base = (char*)d_ws;
  size_t o = 0;
  auto alloc = [&](size_t bytes) -> void* {
    void* ptr = base + o;
    o = (o + bytes + 255) & ~(size_t)255;
    return ptr;
  };
  int* cnt = (int*)alloc((size_t)2 * N * 4);  // cnt + cur contiguous
  int* cur = cnt + N;
  int* off = (int*)alloc((size_t)(N + 1) * 4);
  int* bsum = (int*)alloc(1024);
  int* csr = (int*)alloc((size_t)E * 4);
  float* invd = (float*)alloc((size_t)N * 4);
  _Float16* w1 = (_Float16*)alloc((size_t)128 * 768 * 2);
  _Float16* w2 = (_Float16*)alloc((size_t)64 * 64 * 2);
  _Float16* w3 = (_Float16*)alloc((size_t)32 * 32 * 2);
  _Float16* w4 = (_Float16*)alloc((size_t)16 * 32 * 2);
  _Float16* P1 = (_Float16*)alloc((size_t)N * 64 * 2);
  _Float16* Q1 = (_Float16*)alloc((size_t)N * 64 * 2);
  _Float16* P2 = (_Float16*)alloc((size_t)N * 32 * 2);
  _Float16* Q2 = (_Float16*)alloc((size_t)N * 32 * 2);
  _Float16* P3 = (_Float16*)alloc((size_t)N * 16 * 2);
  _Float16* Q3 = (_Float16*)alloc((size_t)N * 16 * 2);
  _Float16* P4 = (_Float16*)alloc((size_t)N * 8 * 2);
  _Float16* Q4 = (_Float16*)alloc((size_t)N * 8 * 2);

  // zero cnt+cur with a proper kernel (graph-captured hipMemsetAsync was 180 us @ 4.5 GB/s)
  const int n4 = (2 * N + 3) / 4;
  zero_kernel<<<(n4 + 255) / 256, 256, 0, stream>>>((int4*)cnt, n4);
  prep_all_kernel<<<(98304 + 4096 + 1024 + 512 + 255) / 256, 256, 0, stream>>>(
      W1l, W1r, W2l, W2r, W3l, W3r, W4l, W4r, w1, w2, w3, w4);

  deg_kernel<<<(E + 255) / 256, 256, 0, stream>>>(edst, cnt, E);
  const int nb = (N + 1 + 1023) / 1024;
  scan1_kernel<<<nb, 256, 0, stream>>>(cnt, off, bsum, invd, N);
  scan2_kernel<<<1, 128, 0, stream>>>(bsum, nb);
  scan3_kernel<<<(N + 1 + 255) / 256, 256, 0, stream>>>(off, bsum, N + 1);
  sortfill_kernel<<<(E + 255) / 256, 256, 0, stream>>>(esrc, edst, off, cur, csr, E);

  const int gb = (N + 127) / 128;
  // Layer 1: 768 -> 64 (LDS-staged MFMA)
  gemm1_kernel<<<gb, 256, 0, stream>>>(x, w1, b1, P1, Q1, N);
  // Layers 2-4 fused with preceding aggregation
  fused_agg_gemm_kernel<64, 64, 8, 64, 64, 32, 32>
      <<<gb, 256, 0, stream>>>(P1, Q1, off, csr, invd, w2, b2, P2, Q2, N);
  fused_agg_gemm_kernel<32, 32, 4, 32, 32, 16, 16>
      <<<gb, 256, 0, stream>>>(P2, Q2, off, csr, invd, w3, b3, P3, Q3, N);
  fused_agg_gemm_kernel<16, 32, 2, 16, 10, 5, 8>
      <<<gb, 256, 0, stream>>>(P3, Q3, off, csr, invd, w4, b4, P4, Q4, N);
  aggregate_last_kernel<<<(N * 8 + 255) / 256, 256, 0, stream>>>(P4, Q4, off, csr, invd, out, N);
}

// Round 6
// 277.462 us; speedup vs baseline: 1.1395x; 1.1395x over previous
//
#include <hip/hip_runtime.h>

using half8 = __attribute__((ext_vector_type(8))) _Float16;
using f32x4 = __attribute__((ext_vector_type(4))) float;

typedef __attribute__((address_space(3))) unsigned int lds_uint;
typedef __attribute__((address_space(1))) const unsigned int glb_uint;
__device__ __forceinline__ void async_copy16(const void* g, void* l) {
  __builtin_amdgcn_global_load_lds((glb_uint*)g, (lds_uint*)l, 16, 0, 0);
}

// ---------------- fast zero ----------------
__global__ void zero_kernel(int4* __restrict__ p, int n4) {
  int i = blockIdx.x * 256 + threadIdx.x;
  if (i < n4) p[i] = make_int4(0, 0, 0, 0);
}

// ---------------- prep: all 4 layers' weights -> fp16, one kernel ----------------
// w1 [128][768]; w2 [64][64]; w3 [32][32]; w4 [16][32] (k-padded 16->32, col-padded 10->16)
__global__ void prep_all_kernel(const float* __restrict__ W1l, const float* __restrict__ W1r,
                                const float* __restrict__ W2l, const float* __restrict__ W2r,
                                const float* __restrict__ W3l, const float* __restrict__ W3r,
                                const float* __restrict__ W4l, const float* __restrict__ W4r,
                                _Float16* __restrict__ w1, _Float16* __restrict__ w2,
                                _Float16* __restrict__ w3, _Float16* __restrict__ w4) {
  int i = blockIdx.x * 256 + threadIdx.x;
  if (i < 98304) {  // 128*768
    int c = i / 768, k = i - c * 768;
    float v = (c < 64) ? W1l[k * 64 + c] : W1r[k * 64 + (c - 64)];
    w1[i] = (_Float16)v;
  } else if (i < 98304 + 4096) {  // w2: [64][64]
    int j = i - 98304;
    int c = j >> 6, k = j & 63;
    float v = (c < 32) ? W2l[k * 32 + c] : W2r[k * 32 + (c - 32)];
    w2[j] = (_Float16)v;
  } else if (i < 98304 + 4096 + 1024) {  // w3: [32][32]
    int j = i - (98304 + 4096);
    int c = j >> 5, k = j & 31;
    float v = (c < 16) ? W3l[k * 16 + c] : W3r[k * 16 + (c - 16)];
    w3[j] = (_Float16)v;
  } else if (i < 98304 + 4096 + 1024 + 512) {  // w4: [16][32], k<16 real, c<10 real
    int j = i - (98304 + 4096 + 1024);
    int c = j >> 5, k = j & 31;
    float v = 0.f;
    if (k < 16) {
      if (c < 5) v = W4l[k * 5 + c];
      else if (c < 10) v = W4r[k * 5 + (c - 5)];
    }
    w4[j] = (_Float16)v;
  }
}

// ---------------- CSR build ----------------
__global__ void deg_kernel(const int* __restrict__ dst, int* __restrict__ cnt, int e) {
  int i = blockIdx.x * 256 + threadIdx.x;
  if (i < e) atomicAdd(&cnt[dst[i]], 1);
}

__global__ void scan1_kernel(const int* __restrict__ cnt, int* __restrict__ off,
                             int* __restrict__ bsum, float* __restrict__ invd, int nodes) {
  __shared__ int sh[256];
  int tid = threadIdx.x;
  int base = blockIdx.x * 1024 + tid * 4;
  int a0 = (base + 0 < nodes) ? cnt[base + 0] : 0;
  int a1 = (base + 1 < nodes) ? cnt[base + 1] : 0;
  int a2 = (base + 2 < nodes) ? cnt[base + 2] : 0;
  int a3 = (base + 3 < nodes) ? cnt[base + 3] : 0;
  if (base + 0 < nodes) invd[base + 0] = a0 > 0 ? 1.0f / (float)a0 : 0.f;
  if (base + 1 < nodes) invd[base + 1] = a1 > 0 ? 1.0f / (float)a1 : 0.f;
  if (base + 2 < nodes) invd[base + 2] = a2 > 0 ? 1.0f / (float)a2 : 0.f;
  if (base + 3 < nodes) invd[base + 3] = a3 > 0 ? 1.0f / (float)a3 : 0.f;
  int s3 = a0 + a1 + a2 + a3;
  sh[tid] = s3;
  __syncthreads();
  for (int d = 1; d < 256; d <<= 1) {
    int v = (tid >= d) ? sh[tid - d] : 0;
    __syncthreads();
    sh[tid] += v;
    __syncthreads();
  }
  int excl = sh[tid] - s3;
  if (base + 0 <= nodes) off[base + 0] = excl;
  if (base + 1 <= nodes) off[base + 1] = excl + a0;
  if (base + 2 <= nodes) off[base + 2] = excl + a0 + a1;
  if (base + 3 <= nodes) off[base + 3] = excl + a0 + a1 + a2;
  if (tid == 255) bsum[blockIdx.x] = sh[255];
}

__global__ void scan2_kernel(int* __restrict__ bsum, int nb) {
  __shared__ int sh[128];
  int tid = threadIdx.x;
  int v = (tid < nb) ? bsum[tid] : 0;
  sh[tid] = v;
  __syncthreads();
  for (int d = 1; d < 128; d <<= 1) {
    int u = (tid >= d) ? sh[tid - d] : 0;
    __syncthreads();
    sh[tid] += u;
    __syncthreads();
  }
  if (tid < nb) bsum[tid] = sh[tid] - v;
}

__global__ void scan3_kernel(int* __restrict__ off, const int* __restrict__ bsum, int ntot) {
  int i = blockIdx.x * 256 + threadIdx.x;
  if (i < ntot) off[i] += bsum[i >> 10];
}

__global__ void sortfill_kernel(const int* __restrict__ src, const int* __restrict__ dst,
                                const int* __restrict__ off, int* __restrict__ cur,
                                int* __restrict__ csr, int e) {
  int i = blockIdx.x * 256 + threadIdx.x;
  if (i < e) {
    int d = dst[i];
    int pos = atomicAdd(&cur[d], 1);
    csr[off[d] + pos] = src[i];
  }
}

// ---------------- layer-1 MFMA GEMM: A AND B staged via global_load_lds ----------------
// Block: 256 thr (4 waves), tile 128 rows x 128 cols, BK=32, LDS 2x(16K A + 8K B) = 48KB
// -> 3 blocks/CU. Compute phase has ZERO vmem ops (B from LDS), so the only vmcnt wait
// is the end-of-iteration drain AFTER compute (vmcnt in-order retire made the R4 version
// serialize: B global loads issued after the HBM prefetch forced a full prefetch drain
// before the first MFMA).
// Swizzle (both tiles): LDS[row][granule g] = global[row][g ^ (row & MASK)] via per-lane
// source address; LDS dest linear (gload_lds constraint).
__global__ __launch_bounds__(256, 3) void gemm1_kernel(
    const float* __restrict__ x,       // [n][768]
    const _Float16* __restrict__ w16,  // [128][768]
    const float* __restrict__ bias,    // [64]
    _Float16* __restrict__ p, _Float16* __restrict__ q, int n) {
  constexpr int DI = 768, BK = 32, NT = DI / BK;
  __shared__ float aS[2][128 * BK];     // 2 x 16 KB
  __shared__ _Float16 bS[2][128 * BK];  // 2 x 8 KB
  int t = threadIdx.x;
  int lane = t & 63, w = t >> 6;
  int lm = lane & 15, lk = lane >> 4;
  int m0 = blockIdx.x * 128;

  // A staging: 4 ops/wave; linear granule g = (j*4+w)*64 + lane; row = g>>3, gi = g&7
  const float* agp[4];
  int abase[4];
#pragma unroll
  for (int j = 0; j < 4; ++j) {
    int g = (j * 4 + w) * 64 + lane;
    int row = g >> 3, gi = g & 7;
    int gj = gi ^ (row & 7);
    int grow = m0 + row;
    if (grow >= n) grow = n - 1;
    agp[j] = x + (size_t)grow * DI + gj * 4;
    abase[j] = (j * 4 + w) * 256;  // float offset of op base (lane 0)
  }
  // B staging: 2 ops/wave; granule g = (j*4+w)*64 + lane; c = g>>2, gi = g&3
  const _Float16* bgp[2];
  int bbase[2];
#pragma unroll
  for (int j = 0; j < 2; ++j) {
    int g = (j * 4 + w) * 64 + lane;
    int c = g >> 2, gi = g & 3;
    int gj = gi ^ (c & 3);
    bgp[j] = w16 + (size_t)c * DI + gj * 8;
    bbase[j] = (j * 4 + w) * 512;  // half offset of op base (lane 0)
  }

  f32x4 acc[2][8];
#pragma unroll
  for (int mi = 0; mi < 2; ++mi)
#pragma unroll
    for (int ni = 0; ni < 8; ++ni) acc[mi][ni] = (f32x4){0.f, 0.f, 0.f, 0.f};

  // prologue: stage tile 0
#pragma unroll
  for (int j = 0; j < 4; ++j) async_copy16(agp[j], &aS[0][abase[j]]);
#pragma unroll
  for (int j = 0; j < 2; ++j) async_copy16(bgp[j], &bS[0][bbase[j]]);
  asm volatile("s_waitcnt vmcnt(0)" ::: "memory");
  __syncthreads();

  int r0l = w * 32 + lm, r1l = r0l + 16;
  int sw = lm & 7;  // (r0l&7) == (r1l&7) == lm&7
  for (int ts = 0; ts < NT; ++ts) {
    int cur = ts & 1;
    if (ts + 1 < NT) {
      int kc = (ts + 1) * BK;
#pragma unroll
      for (int j = 0; j < 4; ++j) async_copy16(agp[j] + kc, &aS[cur ^ 1][abase[j]]);
#pragma unroll
      for (int j = 0; j < 2; ++j) async_copy16(bgp[j] + kc, &bS[cur ^ 1][bbase[j]]);
    }
    const float* ab = aS[cur];
    const _Float16* bb = bS[cur];
    // A fragments (swizzled granule reads)
    f32x4 v0a = *(const f32x4*)(ab + r0l * 32 + (((lk * 2 + 0) ^ sw) << 2));
    f32x4 v0b = *(const f32x4*)(ab + r0l * 32 + (((lk * 2 + 1) ^ sw) << 2));
    f32x4 v1a = *(const f32x4*)(ab + r1l * 32 + (((lk * 2 + 0) ^ sw) << 2));
    f32x4 v1b = *(const f32x4*)(ab + r1l * 32 + (((lk * 2 + 1) ^ sw) << 2));
    half8 a0, a1;
#pragma unroll
    for (int j = 0; j < 4; ++j) {
      a0[j] = (_Float16)v0a[j]; a0[4 + j] = (_Float16)v0b[j];
      a1[j] = (_Float16)v1a[j]; a1[4 + j] = (_Float16)v1b[j];
    }
    int bsw = (lk ^ (lm & 3)) << 3;
#pragma unroll
    for (int ni = 0; ni < 8; ++ni) {
      half8 b = *(const half8*)(bb + ni * 512 + lm * 32 + bsw);
      acc[0][ni] = __builtin_amdgcn_mfma_f32_16x16x32_f16(a0, b, acc[0][ni], 0, 0, 0);
      acc[1][ni] = __builtin_amdgcn_mfma_f32_16x16x32_f16(a1, b, acc[1][ni], 0, 0, 0);
    }
    asm volatile("s_waitcnt vmcnt(0)" ::: "memory");
    __syncthreads();
  }

  // C/D: col = ni*16 + lm, row = m0 + w*32 + mi*16 + lk*4 + j
#pragma unroll
  for (int mi = 0; mi < 2; ++mi)
#pragma unroll
    for (int ni = 0; ni < 8; ++ni) {
      int col = ni * 16 + lm;
#pragma unroll
      for (int j = 0; j < 4; ++j) {
        int row = m0 + w * 32 + mi * 16 + lk * 4 + j;
        if (row < n) {
          float v = acc[mi][ni][j];
          if (col < 64) p[(size_t)row * 64 + col] = (_Float16)v;
          else q[(size_t)row * 64 + (col - 64)] = (_Float16)(v + bias[col - 64]);
        }
      }
    }
}

// ---------------- fused aggregate(+relu) -> gemm for layers 2-4 ----------------
template <int DIR, int DIP, int PSI, int NC, int NCR, int DO, int PSO>
__global__ __launch_bounds__(256) void fused_agg_gemm_kernel(
    const _Float16* __restrict__ pin, const _Float16* __restrict__ qin,
    const int* __restrict__ off, const int* __restrict__ csr, const float* __restrict__ invd,
    const _Float16* __restrict__ w16, const float* __restrict__ bias,
    _Float16* __restrict__ pout, _Float16* __restrict__ qout, int n) {
  constexpr int SP = DIP + 8;
  constexpr int C8 = DIR / 8;
  constexpr int CT = C8 / 2;
  constexpr int NF = NC / 16;
  __shared__ _Float16 hs[128 * SP];
  int t = threadIdx.x;
  int node_l = t >> 1, half = t & 1;
  int node = blockIdx.x * 128 + node_l;

  if (node < n) {
    int e0 = off[node], e1 = off[node + 1];
    const half8* p8 = (const half8*)pin;
    float s[CT][8];
#pragma unroll
    for (int c = 0; c < CT; ++c)
#pragma unroll
      for (int j = 0; j < 8; ++j) s[c][j] = 0.f;
    for (int e = e0; e < e1; ++e) {
      int src = csr[e];
#pragma unroll
      for (int c = 0; c < CT; ++c) {
        half8 v = p8[(size_t)src * PSI + half * CT + c];
#pragma unroll
        for (int j = 0; j < 8; ++j) s[c][j] += (float)v[j];
      }
    }
    float id = invd[node];
#pragma unroll
    for (int c = 0; c < CT; ++c) {
      half8 qv = ((const half8*)qin)[(size_t)node * PSI + half * CT + c];
      half8 o;
#pragma unroll
      for (int j = 0; j < 8; ++j) o[j] = (_Float16)fmaxf(s[c][j] * id + (float)qv[j], 0.f);
      *(half8*)(hs + node_l * SP + (half * CT + c) * 8) = o;
    }
    if (DIP > DIR) {
      half8 z = {};
      *(half8*)(hs + node_l * SP + (C8 + half) * 8) = z;
    }
  }
  __syncthreads();

  int lane = t & 63, w = t >> 6;
  int lm = lane & 15, lk = lane >> 4;
  int r0l = w * 32 + lm, r1l = r0l + 16;
  const _Float16* wp = w16 + (size_t)lm * DIP + lk * 8;
  f32x4 acc[2][NF];
#pragma unroll
  for (int mi = 0; mi < 2; ++mi)
#pragma unroll
    for (int ni = 0; ni < NF; ++ni) acc[mi][ni] = (f32x4){0.f, 0.f, 0.f, 0.f};
#pragma unroll
  for (int kc = 0; kc < DIP; kc += 32) {
    half8 a0 = *(const half8*)(hs + r0l * SP + kc + lk * 8);
    half8 a1 = *(const half8*)(hs + r1l * SP + kc + lk * 8);
#pragma unroll
    for (int ni = 0; ni < NF; ++ni) {
      half8 b = *(const half8*)(wp + (size_t)ni * 16 * DIP + kc);
      acc[0][ni] = __builtin_amdgcn_mfma_f32_16x16x32_f16(a0, b, acc[0][ni], 0, 0, 0);
      acc[1][ni] = __builtin_amdgcn_mfma_f32_16x16x32_f16(a1, b, acc[1][ni], 0, 0, 0);
    }
  }
#pragma unroll
  for (int mi = 0; mi < 2; ++mi)
#pragma unroll
    for (int ni = 0; ni < NF; ++ni) {
      int col = ni * 16 + lm;
      if (col >= NCR) continue;
#pragma unroll
      for (int j = 0; j < 4; ++j) {
        int row = blockIdx.x * 128 + w * 32 + mi * 16 + lk * 4 + j;
        if (row < n) {
          float v = acc[mi][ni][j];
          if (col < DO) pout[(size_t)row * PSO + col] = (_Float16)v;
          else qout[(size_t)row * PSO + (col - DO)] = (_Float16)(v + bias[col - DO]);
        }
      }
    }
}

// final aggregation: p,q fp16 [n][8] (cols 0-4 valid), out fp32 [n][5]
__global__ __launch_bounds__(256) void aggregate_last_kernel(
    const _Float16* __restrict__ p, const _Float16* __restrict__ q,
    const int* __restrict__ off, const int* __restrict__ csr,
    const float* __restrict__ invd, float* __restrict__ out, int n) {
  int t = blockIdx.x * 256 + threadIdx.x;
  int node = t >> 3;
  int c = t & 7;
  if (node >= n || c >= 5) return;
  int e0 = off[node], e1 = off[node + 1];
  float s = 0.f;
  for (int e = e0; e < e1; ++e) s += (float)p[(size_t)csr[e] * 8 + c];
  out[(size_t)node * 5 + c] = s * invd[node] + (float)q[(size_t)node * 8 + c];
}

// ---------------- launch ----------------
extern "C" void kernel_launch(void* const* d_in, const int* in_sizes, int n_in,
                              void* d_out, int out_size, void* d_ws, size_t ws_size,
                              hipStream_t stream) {
  const float* x = (const float*)d_in[0];
  const int* ei = (const int*)d_in[1];
  const int E = in_sizes[1] / 2;
  const int* esrc = ei;
  const int* edst = ei + E;
  const float* W1l = (const float*)d_in[3];
  const float* W1r = (const float*)d_in[4];
  const float* b1 = (const float*)d_in[5];
  const float* W2l = (const float*)d_in[6];
  const float* W2r = (const float*)d_in[7];
  const float* b2 = (const float*)d_in[8];
  const float* W3l = (const float*)d_in[9];
  const float* W3r = (const float*)d_in[10];
  const float* b3 = (const float*)d_in[11];
  const float* W4l = (const float*)d_in[12];
  const float* W4r = (const float*)d_in[13];
  const float* b4 = (const float*)d_in[14];
  const int N = in_sizes[0] / 768;
  float* out = (float*)d_out;
  (void)n_in; (void)out_size; (void)ws_size;

  char* base = (char*)d_ws;
  size_t o = 0;
  auto alloc = [&](size_t bytes) -> void* {
    void* ptr = base + o;
    o = (o + bytes + 255) & ~(size_t)255;
    return ptr;
  };
  int* cnt = (int*)alloc((size_t)2 * N * 4);  // cnt + cur contiguous
  int* cur = cnt + N;
  int* off = (int*)alloc((size_t)(N + 1) * 4);
  int* bsum = (int*)alloc(1024);
  int* csr = (int*)alloc((size_t)E * 4);
  float* invd = (float*)alloc((size_t)N * 4);
  _Float16* w1 = (_Float16*)alloc((size_t)128 * 768 * 2);
  _Float16* w2 = (_Float16*)alloc((size_t)64 * 64 * 2);
  _Float16* w3 = (_Float16*)alloc((size_t)32 * 32 * 2);
  _Float16* w4 = (_Float16*)alloc((size_t)16 * 32 * 2);
  _Float16* P1 = (_Float16*)alloc((size_t)N * 64 * 2);
  _Float16* Q1 = (_Float16*)alloc((size_t)N * 64 * 2);
  _Float16* P2 = (_Float16*)alloc((size_t)N * 32 * 2);
  _Float16* Q2 = (_Float16*)alloc((size_t)N * 32 * 2);
  _Float16* P3 = (_Float16*)alloc((size_t)N * 16 * 2);
  _Float16* Q3 = (_Float16*)alloc((size_t)N * 16 * 2);
  _Float16* P4 = (_Float16*)alloc((size_t)N * 8 * 2);
  _Float16* Q4 = (_Float16*)alloc((size_t)N * 8 * 2);

  const int n4 = (2 * N + 3) / 4;
  zero_kernel<<<(n4 + 255) / 256, 256, 0, stream>>>((int4*)cnt, n4);
  prep_all_kernel<<<(98304 + 4096 + 1024 + 512 + 255) / 256, 256, 0, stream>>>(
      W1l, W1r, W2l, W2r, W3l, W3r, W4l, W4r, w1, w2, w3, w4);

  deg_kernel<<<(E + 255) / 256, 256, 0, stream>>>(edst, cnt, E);
  const int nb = (N + 1 + 1023) / 1024;
  scan1_kernel<<<nb, 256, 0, stream>>>(cnt, off, bsum, invd, N);
  scan2_kernel<<<1, 128, 0, stream>>>(bsum, nb);
  scan3_kernel<<<(N + 1 + 255) / 256, 256, 0, stream>>>(off, bsum, N + 1);
  sortfill_kernel<<<(E + 255) / 256, 256, 0, stream>>>(esrc, edst, off, cur, csr, E);

  const int gb = (N + 127) / 128;
  // Layer 1: 768 -> 64 (A+B LDS-staged MFMA, 2-phase)
  gemm1_kernel<<<gb, 256, 0, stream>>>(x, w1, b1, P1, Q1, N);
  // Layers 2-4 fused with preceding aggregation
  fused_agg_gemm_kernel<64, 64, 8, 64, 64, 32, 32>
      <<<gb, 256, 0, stream>>>(P1, Q1, off, csr, invd, w2, b2, P2, Q2, N);
  fused_agg_gemm_kernel<32, 32, 4, 32, 32, 16, 16>
      <<<gb, 256, 0, stream>>>(P2, Q2, off, csr, invd, w3, b3, P3, Q3, N);
  fused_agg_gemm_kernel<16, 32, 2, 16, 10, 5, 8>
      <<<gb, 256, 0, stream>>>(P3, Q3, off, csr, invd, w4, b4, P4, Q4, N);
  aggregate_last_kernel<<<(N * 8 + 255) / 256, 256, 0, stream>>>(P4, Q4, off, csr, invd, out, N);
}

// Round 7
// 270.590 us; speedup vs baseline: 1.1685x; 1.0254x over previous
//
#include <hip/hip_runtime.h>

using half8 = __attribute__((ext_vector_type(8))) _Float16;
using f32x4 = __attribute__((ext_vector_type(4))) float;

typedef __attribute__((address_space(3))) unsigned int lds_uint;
typedef __attribute__((address_space(1))) const unsigned int glb_uint;
__device__ __forceinline__ void async_copy16(const void* g, void* l) {
  __builtin_amdgcn_global_load_lds((glb_uint*)g, (lds_uint*)l, 16, 0, 0);
}

// ---------------- fast zero ----------------
__global__ void zero_kernel(int4* __restrict__ p, int n4) {
  int i = blockIdx.x * 256 + threadIdx.x;
  if (i < n4) p[i] = make_int4(0, 0, 0, 0);
}

// ---------------- prep: all 4 layers' weights -> fp16, one kernel ----------------
// w1 [128][768]; w2 [64][64]; w3 [32][32]; w4 [16][32] (k-padded 16->32, col-padded 10->16)
__global__ void prep_all_kernel(const float* __restrict__ W1l, const float* __restrict__ W1r,
                                const float* __restrict__ W2l, const float* __restrict__ W2r,
                                const float* __restrict__ W3l, const float* __restrict__ W3r,
                                const float* __restrict__ W4l, const float* __restrict__ W4r,
                                _Float16* __restrict__ w1, _Float16* __restrict__ w2,
                                _Float16* __restrict__ w3, _Float16* __restrict__ w4) {
  int i = blockIdx.x * 256 + threadIdx.x;
  if (i < 98304) {  // 128*768
    int c = i / 768, k = i - c * 768;
    float v = (c < 64) ? W1l[k * 64 + c] : W1r[k * 64 + (c - 64)];
    w1[i] = (_Float16)v;
  } else if (i < 98304 + 4096) {  // w2: [64][64]
    int j = i - 98304;
    int c = j >> 6, k = j & 63;
    float v = (c < 32) ? W2l[k * 32 + c] : W2r[k * 32 + (c - 32)];
    w2[j] = (_Float16)v;
  } else if (i < 98304 + 4096 + 1024) {  // w3: [32][32]
    int j = i - (98304 + 4096);
    int c = j >> 5, k = j & 31;
    float v = (c < 16) ? W3l[k * 16 + c] : W3r[k * 16 + (c - 16)];
    w3[j] = (_Float16)v;
  } else if (i < 98304 + 4096 + 1024 + 512) {  // w4: [16][32], k<16 real, c<10 real
    int j = i - (98304 + 4096 + 1024);
    int c = j >> 5, k = j & 31;
    float v = 0.f;
    if (k < 16) {
      if (c < 5) v = W4l[k * 5 + c];
      else if (c < 10) v = W4r[k * 5 + (c - 5)];
    }
    w4[j] = (_Float16)v;
  }
}

// ---------------- CSR build ----------------
__global__ void deg_kernel(const int* __restrict__ dst, int* __restrict__ cnt, int e) {
  int i = blockIdx.x * 256 + threadIdx.x;
  if (i < e) atomicAdd(&cnt[dst[i]], 1);
}

__global__ void scan1_kernel(const int* __restrict__ cnt, int* __restrict__ off,
                             int* __restrict__ bsum, float* __restrict__ invd, int nodes) {
  __shared__ int sh[256];
  int tid = threadIdx.x;
  int base = blockIdx.x * 1024 + tid * 4;
  int a0 = (base + 0 < nodes) ? cnt[base + 0] : 0;
  int a1 = (base + 1 < nodes) ? cnt[base + 1] : 0;
  int a2 = (base + 2 < nodes) ? cnt[base + 2] : 0;
  int a3 = (base + 3 < nodes) ? cnt[base + 3] : 0;
  if (base + 0 < nodes) invd[base + 0] = a0 > 0 ? 1.0f / (float)a0 : 0.f;
  if (base + 1 < nodes) invd[base + 1] = a1 > 0 ? 1.0f / (float)a1 : 0.f;
  if (base + 2 < nodes) invd[base + 2] = a2 > 0 ? 1.0f / (float)a2 : 0.f;
  if (base + 3 < nodes) invd[base + 3] = a3 > 0 ? 1.0f / (float)a3 : 0.f;
  int s3 = a0 + a1 + a2 + a3;
  sh[tid] = s3;
  __syncthreads();
  for (int d = 1; d < 256; d <<= 1) {
    int v = (tid >= d) ? sh[tid - d] : 0;
    __syncthreads();
    sh[tid] += v;
    __syncthreads();
  }
  int excl = sh[tid] - s3;
  if (base + 0 <= nodes) off[base + 0] = excl;
  if (base + 1 <= nodes) off[base + 1] = excl + a0;
  if (base + 2 <= nodes) off[base + 2] = excl + a0 + a1;
  if (base + 3 <= nodes) off[base + 3] = excl + a0 + a1 + a2;
  if (tid == 255) bsum[blockIdx.x] = sh[255];
}

__global__ void scan2_kernel(int* __restrict__ bsum, int nb) {
  __shared__ int sh[128];
  int tid = threadIdx.x;
  int v = (tid < nb) ? bsum[tid] : 0;
  sh[tid] = v;
  __syncthreads();
  for (int d = 1; d < 128; d <<= 1) {
    int u = (tid >= d) ? sh[tid - d] : 0;
    __syncthreads();
    sh[tid] += u;
    __syncthreads();
  }
  if (tid < nb) bsum[tid] = sh[tid] - v;
}

__global__ void scan3_kernel(int* __restrict__ off, const int* __restrict__ bsum, int ntot) {
  int i = blockIdx.x * 256 + threadIdx.x;
  if (i < ntot) off[i] += bsum[i >> 10];
}

__global__ void sortfill_kernel(const int* __restrict__ src, const int* __restrict__ dst,
                                const int* __restrict__ off, int* __restrict__ cur,
                                int* __restrict__ csr, int e) {
  int i = blockIdx.x * 256 + threadIdx.x;
  if (i < e) {
    int d = dst[i];
    int pos = atomicAdd(&cur[d], 1);
    csr[off[d] + pos] = src[i];
  }
}

// ---------------- layer-1 MFMA GEMM: A+B via global_load_lds, counted-vmcnt pipeline ----
// Block: 256 thr (4 waves), tile 128 rows x 128 cols, BK=32, LDS 2x(16K A + 8K B) = 48KB
// -> 3 blocks/CU. Schedule (T3/T4): issue tile ts+1 (6 ops/thread), then vmcnt(6) waits
// ONLY tile ts's ops (issued one full iteration earlier; in-order retire makes the count
// exact) -> barrier -> compute -> barrier. Never drains the just-issued prefetch, so HBM
// latency+delivery hides under the previous iteration's compute.
__global__ __launch_bounds__(256, 3) void gemm1_kernel(
    const float* __restrict__ x,       // [n][768]
    const _Float16* __restrict__ w16,  // [128][768]
    const float* __restrict__ bias,    // [64]
    _Float16* __restrict__ p, _Float16* __restrict__ q, int n) {
  constexpr int DI = 768, BK = 32, NT = DI / BK;
  __shared__ float aS[2][128 * BK];     // 2 x 16 KB
  __shared__ _Float16 bS[2][128 * BK];  // 2 x 8 KB
  int t = threadIdx.x;
  int lane = t & 63, w = t >> 6;
  int lm = lane & 15, lk = lane >> 4;
  int m0 = blockIdx.x * 128;

  // A staging: 4 ops/wave; linear granule g = (j*4+w)*64 + lane; row = g>>3, gi = g&7
  // swizzle: LDS slot gi holds global granule gi ^ (row&7)
  const float* agp[4];
  int abase[4];
#pragma unroll
  for (int j = 0; j < 4; ++j) {
    int g = (j * 4 + w) * 64 + lane;
    int row = g >> 3, gi = g & 7;
    int gj = gi ^ (row & 7);
    int grow = m0 + row;
    if (grow >= n) grow = n - 1;
    agp[j] = x + (size_t)grow * DI + gj * 4;
    abase[j] = (j * 4 + w) * 256;  // float offset of op base (lane 0)
  }
  // B staging: 2 ops/wave; granule g = (j*4+w)*64 + lane; c = g>>2, gi = g&3
  // swizzle: gi ^ ((c>>1)&3) -> same-parity lanes spread over all 4 slots (2-way, free)
  const _Float16* bgp[2];
  int bbase[2];
#pragma unroll
  for (int j = 0; j < 2; ++j) {
    int g = (j * 4 + w) * 64 + lane;
    int c = g >> 2, gi = g & 3;
    int gj = gi ^ ((c >> 1) & 3);
    bgp[j] = w16 + (size_t)c * DI + gj * 8;
    bbase[j] = (j * 4 + w) * 512;  // half offset of op base (lane 0)
  }

  f32x4 acc[2][8];
#pragma unroll
  for (int mi = 0; mi < 2; ++mi)
#pragma unroll
    for (int ni = 0; ni < 8; ++ni) acc[mi][ni] = (f32x4){0.f, 0.f, 0.f, 0.f};

  int r0l = w * 32 + lm, r1l = r0l + 16;
  int sw = lm & 7;                     // A-read swizzle ((r&7) same for r0l/r1l)
  int bsw = (lk ^ ((lm >> 1) & 3)) << 3;  // B-read swizzle (halfs)

  auto compute_tile = [&](const float* ab, const _Float16* bb) {
    f32x4 v0a = *(const f32x4*)(ab + r0l * 32 + (((lk * 2 + 0) ^ sw) << 2));
    f32x4 v0b = *(const f32x4*)(ab + r0l * 32 + (((lk * 2 + 1) ^ sw) << 2));
    f32x4 v1a = *(const f32x4*)(ab + r1l * 32 + (((lk * 2 + 0) ^ sw) << 2));
    f32x4 v1b = *(const f32x4*)(ab + r1l * 32 + (((lk * 2 + 1) ^ sw) << 2));
    half8 a0, a1;
#pragma unroll
    for (int j = 0; j < 4; ++j) {
      a0[j] = (_Float16)v0a[j]; a0[4 + j] = (_Float16)v0b[j];
      a1[j] = (_Float16)v1a[j]; a1[4 + j] = (_Float16)v1b[j];
    }
#pragma unroll
    for (int ni = 0; ni < 8; ++ni) {
      half8 b = *(const half8*)(bb + ni * 512 + lm * 32 + bsw);
      acc[0][ni] = __builtin_amdgcn_mfma_f32_16x16x32_f16(a0, b, acc[0][ni], 0, 0, 0);
      acc[1][ni] = __builtin_amdgcn_mfma_f32_16x16x32_f16(a1, b, acc[1][ni], 0, 0, 0);
    }
  };

  // prologue: stage tile 0
#pragma unroll
  for (int j = 0; j < 4; ++j) async_copy16(agp[j], &aS[0][abase[j]]);
#pragma unroll
  for (int j = 0; j < 2; ++j) async_copy16(bgp[j], &bS[0][bbase[j]]);

  for (int ts = 0; ts < NT - 1; ++ts) {
    int cur = ts & 1;
    int kc = (ts + 1) * BK;
#pragma unroll
    for (int j = 0; j < 4; ++j) async_copy16(agp[j] + kc, &aS[cur ^ 1][abase[j]]);
#pragma unroll
    for (int j = 0; j < 2; ++j) async_copy16(bgp[j] + kc, &bS[cur ^ 1][bbase[j]]);
    asm volatile("s_waitcnt vmcnt(6)" ::: "memory");  // tile ts landed (6 newer in flight)
    __syncthreads();
    compute_tile(aS[cur], bS[cur]);
    __syncthreads();  // all waves done reading buf[cur] before iter ts+1 overwrites it
  }
  // epilogue: last tile
  asm volatile("s_waitcnt vmcnt(0)" ::: "memory");
  __syncthreads();
  compute_tile(aS[(NT - 1) & 1], bS[(NT - 1) & 1]);

  // C/D: col = ni*16 + lm, row = m0 + w*32 + mi*16 + lk*4 + j
#pragma unroll
  for (int mi = 0; mi < 2; ++mi)
#pragma unroll
    for (int ni = 0; ni < 8; ++ni) {
      int col = ni * 16 + lm;
#pragma unroll
      for (int j = 0; j < 4; ++j) {
        int row = m0 + w * 32 + mi * 16 + lk * 4 + j;
        if (row < n) {
          float v = acc[mi][ni][j];
          if (col < 64) p[(size_t)row * 64 + col] = (_Float16)v;
          else q[(size_t)row * 64 + (col - 64)] = (_Float16)(v + bias[col - 64]);
        }
      }
    }
}

// ---------------- fused aggregate(+relu) -> gemm for layers 2-4 ----------------
template <int DIR, int DIP, int PSI, int NC, int NCR, int DO, int PSO>
__global__ __launch_bounds__(256) void fused_agg_gemm_kernel(
    const _Float16* __restrict__ pin, const _Float16* __restrict__ qin,
    const int* __restrict__ off, const int* __restrict__ csr, const float* __restrict__ invd,
    const _Float16* __restrict__ w16, const float* __restrict__ bias,
    _Float16* __restrict__ pout, _Float16* __restrict__ qout, int n) {
  constexpr int SP = DIP + 8;
  constexpr int C8 = DIR / 8;
  constexpr int CT = C8 / 2;
  constexpr int NF = NC / 16;
  __shared__ _Float16 hs[128 * SP];
  int t = threadIdx.x;
  int node_l = t >> 1, half = t & 1;
  int node = blockIdx.x * 128 + node_l;

  if (node < n) {
    int e0 = off[node], e1 = off[node + 1];
    const half8* p8 = (const half8*)pin;
    float s[CT][8];
#pragma unroll
    for (int c = 0; c < CT; ++c)
#pragma unroll
      for (int j = 0; j < 8; ++j) s[c][j] = 0.f;
    for (int e = e0; e < e1; ++e) {
      int src = csr[e];
#pragma unroll
      for (int c = 0; c < CT; ++c) {
        half8 v = p8[(size_t)src * PSI + half * CT + c];
#pragma unroll
        for (int j = 0; j < 8; ++j) s[c][j] += (float)v[j];
      }
    }
    float id = invd[node];
#pragma unroll
    for (int c = 0; c < CT; ++c) {
      half8 qv = ((const half8*)qin)[(size_t)node * PSI + half * CT + c];
      half8 o;
#pragma unroll
      for (int j = 0; j < 8; ++j) o[j] = (_Float16)fmaxf(s[c][j] * id + (float)qv[j], 0.f);
      *(half8*)(hs + node_l * SP + (half * CT + c) * 8) = o;
    }
    if (DIP > DIR) {
      half8 z = {};
      *(half8*)(hs + node_l * SP + (C8 + half) * 8) = z;
    }
  }
  __syncthreads();

  int lane = t & 63, w = t >> 6;
  int lm = lane & 15, lk = lane >> 4;
  int r0l = w * 32 + lm, r1l = r0l + 16;
  const _Float16* wp = w16 + (size_t)lm * DIP + lk * 8;
  f32x4 acc[2][NF];
#pragma unroll
  for (int mi = 0; mi < 2; ++mi)
#pragma unroll
    for (int ni = 0; ni < NF; ++ni) acc[mi][ni] = (f32x4){0.f, 0.f, 0.f, 0.f};
#pragma unroll
  for (int kc = 0; kc < DIP; kc += 32) {
    half8 a0 = *(const half8*)(hs + r0l * SP + kc + lk * 8);
    half8 a1 = *(const half8*)(hs + r1l * SP + kc + lk * 8);
#pragma unroll
    for (int ni = 0; ni < NF; ++ni) {
      half8 b = *(const half8*)(wp + (size_t)ni * 16 * DIP + kc);
      acc[0][ni] = __builtin_amdgcn_mfma_f32_16x16x32_f16(a0, b, acc[0][ni], 0, 0, 0);
      acc[1][ni] = __builtin_amdgcn_mfma_f32_16x16x32_f16(a1, b, acc[1][ni], 0, 0, 0);
    }
  }
#pragma unroll
  for (int mi = 0; mi < 2; ++mi)
#pragma unroll
    for (int ni = 0; ni < NF; ++ni) {
      int col = ni * 16 + lm;
      if (col >= NCR) continue;
#pragma unroll
      for (int j = 0; j < 4; ++j) {
        int row = blockIdx.x * 128 + w * 32 + mi * 16 + lk * 4 + j;
        if (row < n) {
          float v = acc[mi][ni][j];
          if (col < DO) pout[(size_t)row * PSO + col] = (_Float16)v;
          else qout[(size_t)row * PSO + (col - DO)] = (_Float16)(v + bias[col - DO]);
        }
      }
    }
}

// final aggregation: p,q fp16 [n][8] (cols 0-4 valid), out fp32 [n][5]
__global__ __launch_bounds__(256) void aggregate_last_kernel(
    const _Float16* __restrict__ p, const _Float16* __restrict__ q,
    const int* __restrict__ off, const int* __restrict__ csr,
    const float* __restrict__ invd, float* __restrict__ out, int n) {
  int t = blockIdx.x * 256 + threadIdx.x;
  int node = t >> 3;
  int c = t & 7;
  if (node >= n || c >= 5) return;
  int e0 = off[node], e1 = off[node + 1];
  float s = 0.f;
  for (int e = e0; e < e1; ++e) s += (float)p[(size_t)csr[e] * 8 + c];
  out[(size_t)node * 5 + c] = s * invd[node] + (float)q[(size_t)node * 8 + c];
}

// ---------------- launch ----------------
extern "C" void kernel_launch(void* const* d_in, const int* in_sizes, int n_in,
                              void* d_out, int out_size, void* d_ws, size_t ws_size,
                              hipStream_t stream) {
  const float* x = (const float*)d_in[0];
  const int* ei = (const int*)d_in[1];
  const int E = in_sizes[1] / 2;
  const int* esrc = ei;
  const int* edst = ei + E;
  const float* W1l = (const float*)d_in[3];
  const float* W1r = (const float*)d_in[4];
  const float* b1 = (const float*)d_in[5];
  const float* W2l = (const float*)d_in[6];
  const float* W2r = (const float*)d_in[7];
  const float* b2 = (const float*)d_in[8];
  const float* W3l = (const float*)d_in[9];
  const float* W3r = (const float*)d_in[10];
  const float* b3 = (const float*)d_in[11];
  const float* W4l = (const float*)d_in[12];
  const float* W4r = (const float*)d_in[13];
  const float* b4 = (const float*)d_in[14];
  const int N = in_sizes[0] / 768;
  float* out = (float*)d_out;
  (void)n_in; (void)out_size; (void)ws_size;

  char* base = (char*)d_ws;
  size_t o = 0;
  auto alloc = [&](size_t bytes) -> void* {
    void* ptr = base + o;
    o = (o + bytes + 255) & ~(size_t)255;
    return ptr;
  };
  int* cnt = (int*)alloc((size_t)2 * N * 4);  // cnt + cur contiguous
  int* cur = cnt + N;
  int* off = (int*)alloc((size_t)(N + 1) * 4);
  int* bsum = (int*)alloc(1024);
  int* csr = (int*)alloc((size_t)E * 4);
  float* invd = (float*)alloc((size_t)N * 4);
  _Float16* w1 = (_Float16*)alloc((size_t)128 * 768 * 2);
  _Float16* w2 = (_Float16*)alloc((size_t)64 * 64 * 2);
  _Float16* w3 = (_Float16*)alloc((size_t)32 * 32 * 2);
  _Float16* w4 = (_Float16*)alloc((size_t)16 * 32 * 2);
  _Float16* P1 = (_Float16*)alloc((size_t)N * 64 * 2);
  _Float16* Q1 = (_Float16*)alloc((size_t)N * 64 * 2);
  _Float16* P2 = (_Float16*)alloc((size_t)N * 32 * 2);
  _Float16* Q2 = (_Float16*)alloc((size_t)N * 32 * 2);
  _Float16* P3 = (_Float16*)alloc((size_t)N * 16 * 2);
  _Float16* Q3 = (_Float16*)alloc((size_t)N * 16 * 2);
  _Float16* P4 = (_Float16*)alloc((size_t)N * 8 * 2);
  _Float16* Q4 = (_Float16*)alloc((size_t)N * 8 * 2);

  const int n4 = (2 * N + 3) / 4;
  zero_kernel<<<(n4 + 255) / 256, 256, 0, stream>>>((int4*)cnt, n4);
  prep_all_kernel<<<(98304 + 4096 + 1024 + 512 + 255) / 256, 256, 0, stream>>>(
      W1l, W1r, W2l, W2r, W3l, W3r, W4l, W4r, w1, w2, w3, w4);

  deg_kernel<<<(E + 255) / 256, 256, 0, stream>>>(edst, cnt, E);
  const int nb = (N + 1 + 1023) / 1024;
  scan1_kernel<<<nb, 256, 0, stream>>>(cnt, off, bsum, invd, N);
  scan2_kernel<<<1, 128, 0, stream>>>(bsum, nb);
  scan3_kernel<<<(N + 1 + 255) / 256, 256, 0, stream>>>(off, bsum, N + 1);
  sortfill_kernel<<<(E + 255) / 256, 256, 0, stream>>>(esrc, edst, off, cur, csr, E);

  const int gb = (N + 127) / 128;
  // Layer 1: 768 -> 64 (A+B LDS-staged MFMA, counted-vmcnt pipeline)
  gemm1_kernel<<<gb, 256, 0, stream>>>(x, w1, b1, P1, Q1, N);
  // Layers 2-4 fused with preceding aggregation
  fused_agg_gemm_kernel<64, 64, 8, 64, 64, 32, 32>
      <<<gb, 256, 0, stream>>>(P1, Q1, off, csr, invd, w2, b2, P2, Q2, N);
  fused_agg_gemm_kernel<32, 32, 4, 32, 32, 16, 16>
      <<<gb, 256, 0, stream>>>(P2, Q2, off, csr, invd, w3, b3, P3, Q3, N);
  fused_agg_gemm_kernel<16, 32, 2, 16, 10, 5, 8>
      <<<gb, 256, 0, stream>>>(P3, Q3, off, csr, invd, w4, b4, P4, Q4, N);
  aggregate_last_kernel<<<(N * 8 + 255) / 256, 256, 0, stream>>>(P4, Q4, off, csr, invd, out, N);
}

// Round 8
// 269.765 us; speedup vs baseline: 1.1721x; 1.0031x over previous
//
#include <hip/hip_runtime.h>

using half8 = __attribute__((ext_vector_type(8))) _Float16;
using f32x4 = __attribute__((ext_vector_type(4))) float;

typedef __attribute__((address_space(3))) unsigned int lds_uint;
typedef __attribute__((address_space(1))) const unsigned int glb_uint;
__device__ __forceinline__ void async_copy16(const void* g, void* l) {
  __builtin_amdgcn_global_load_lds((glb_uint*)g, (lds_uint*)l, 16, 0, 0);
}

// raw workgroup barrier WITHOUT the implicit vmcnt(0)/lgkmcnt(0) drain that
// __syncthreads() emits ([HIP-compiler]): the counted-vmcnt pipeline depends on
// NOT draining the just-issued prefetch at the barrier.
__device__ __forceinline__ void raw_barrier() {
  asm volatile("" ::: "memory");
  __builtin_amdgcn_s_barrier();
  asm volatile("" ::: "memory");
}

// ---------------- fast zero ----------------
__global__ void zero_kernel(int4* __restrict__ p, int n4) {
  int i = blockIdx.x * 256 + threadIdx.x;
  if (i < n4) p[i] = make_int4(0, 0, 0, 0);
}

// ---------------- prep: all 4 layers' weights -> fp16, one kernel ----------------
// w1 [128][768]; w2 [64][64]; w3 [32][32]; w4 [16][32] (k-padded 16->32, col-padded 10->16)
__global__ void prep_all_kernel(const float* __restrict__ W1l, const float* __restrict__ W1r,
                                const float* __restrict__ W2l, const float* __restrict__ W2r,
                                const float* __restrict__ W3l, const float* __restrict__ W3r,
                                const float* __restrict__ W4l, const float* __restrict__ W4r,
                                _Float16* __restrict__ w1, _Float16* __restrict__ w2,
                                _Float16* __restrict__ w3, _Float16* __restrict__ w4) {
  int i = blockIdx.x * 256 + threadIdx.x;
  if (i < 98304) {  // 128*768
    int c = i / 768, k = i - c * 768;
    float v = (c < 64) ? W1l[k * 64 + c] : W1r[k * 64 + (c - 64)];
    w1[i] = (_Float16)v;
  } else if (i < 98304 + 4096) {  // w2: [64][64]
    int j = i - 98304;
    int c = j >> 6, k = j & 63;
    float v = (c < 32) ? W2l[k * 32 + c] : W2r[k * 32 + (c - 32)];
    w2[j] = (_Float16)v;
  } else if (i < 98304 + 4096 + 1024) {  // w3: [32][32]
    int j = i - (98304 + 4096);
    int c = j >> 5, k = j & 31;
    float v = (c < 16) ? W3l[k * 16 + c] : W3r[k * 16 + (c - 16)];
    w3[j] = (_Float16)v;
  } else if (i < 98304 + 4096 + 1024 + 512) {  // w4: [16][32], k<16 real, c<10 real
    int j = i - (98304 + 4096 + 1024);
    int c = j >> 5, k = j & 31;
    float v = 0.f;
    if (k < 16) {
      if (c < 5) v = W4l[k * 5 + c];
      else if (c < 10) v = W4r[k * 5 + (c - 5)];
    }
    w4[j] = (_Float16)v;
  }
}

// ---------------- CSR build ----------------
__global__ void deg_kernel(const int* __restrict__ dst, int* __restrict__ cnt, int e) {
  int i = blockIdx.x * 256 + threadIdx.x;
  if (i < e) atomicAdd(&cnt[dst[i]], 1);
}

__global__ void scan1_kernel(const int* __restrict__ cnt, int* __restrict__ off,
                             int* __restrict__ bsum, float* __restrict__ invd, int nodes) {
  __shared__ int sh[256];
  int tid = threadIdx.x;
  int base = blockIdx.x * 1024 + tid * 4;
  int a0 = (base + 0 < nodes) ? cnt[base + 0] : 0;
  int a1 = (base + 1 < nodes) ? cnt[base + 1] : 0;
  int a2 = (base + 2 < nodes) ? cnt[base + 2] : 0;
  int a3 = (base + 3 < nodes) ? cnt[base + 3] : 0;
  if (base + 0 < nodes) invd[base + 0] = a0 > 0 ? 1.0f / (float)a0 : 0.f;
  if (base + 1 < nodes) invd[base + 1] = a1 > 0 ? 1.0f / (float)a1 : 0.f;
  if (base + 2 < nodes) invd[base + 2] = a2 > 0 ? 1.0f / (float)a2 : 0.f;
  if (base + 3 < nodes) invd[base + 3] = a3 > 0 ? 1.0f / (float)a3 : 0.f;
  int s3 = a0 + a1 + a2 + a3;
  sh[tid] = s3;
  __syncthreads();
  for (int d = 1; d < 256; d <<= 1) {
    int v = (tid >= d) ? sh[tid - d] : 0;
    __syncthreads();
    sh[tid] += v;
    __syncthreads();
  }
  int excl = sh[tid] - s3;
  if (base + 0 <= nodes) off[base + 0] = excl;
  if (base + 1 <= nodes) off[base + 1] = excl + a0;
  if (base + 2 <= nodes) off[base + 2] = excl + a0 + a1;
  if (base + 3 <= nodes) off[base + 3] = excl + a0 + a1 + a2;
  if (tid == 255) bsum[blockIdx.x] = sh[255];
}

__global__ void scan2_kernel(int* __restrict__ bsum, int nb) {
  __shared__ int sh[128];
  int tid = threadIdx.x;
  int v = (tid < nb) ? bsum[tid] : 0;
  sh[tid] = v;
  __syncthreads();
  for (int d = 1; d < 128; d <<= 1) {
    int u = (tid >= d) ? sh[tid - d] : 0;
    __syncthreads();
    sh[tid] += u;
    __syncthreads();
  }
  if (tid < nb) bsum[tid] = sh[tid] - v;
}

__global__ void scan3_kernel(int* __restrict__ off, const int* __restrict__ bsum, int ntot) {
  int i = blockIdx.x * 256 + threadIdx.x;
  if (i < ntot) off[i] += bsum[i >> 10];
}

__global__ void sortfill_kernel(const int* __restrict__ src, const int* __restrict__ dst,
                                const int* __restrict__ off, int* __restrict__ cur,
                                int* __restrict__ csr, int e) {
  int i = blockIdx.x * 256 + threadIdx.x;
  if (i < e) {
    int d = dst[i];
    int pos = atomicAdd(&cur[d], 1);
    csr[off[d] + pos] = src[i];
  }
}

// ---------------- layer-1 MFMA GEMM: A+B via global_load_lds, counted-vmcnt pipeline ----
// Block: 256 thr (4 waves), tile 128 rows x 128 cols, BK=32, LDS 2x(16K A + 8K B) = 48KB
// -> 3 blocks/CU. Per iter: issue tile ts+1 (6 gload_lds/thread) -> vmcnt(6) (retires
// exactly tile ts's 6, in-order) -> RAW s_barrier (no drain!) -> compute -> raw barrier.
// R7 used __syncthreads(), whose implicit vmcnt(0) drain nullified the counted scheme.
__global__ __launch_bounds__(256, 3) void gemm1_kernel(
    const float* __restrict__ x,       // [n][768]
    const _Float16* __restrict__ w16,  // [128][768]
    const float* __restrict__ bias,    // [64]
    _Float16* __restrict__ p, _Float16* __restrict__ q, int n) {
  constexpr int DI = 768, BK = 32, NT = DI / BK;
  __shared__ float aS[2][128 * BK];     // 2 x 16 KB
  __shared__ _Float16 bS[2][128 * BK];  // 2 x 8 KB
  int t = threadIdx.x;
  int lane = t & 63, w = t >> 6;
  int lm = lane & 15, lk = lane >> 4;
  int m0 = blockIdx.x * 128;

  // A staging: 4 ops/wave; linear granule g = (j*4+w)*64 + lane; row = g>>3, gi = g&7
  // swizzle: LDS slot gi holds global granule gi ^ (row&7)
  const float* agp[4];
  int abase[4];
#pragma unroll
  for (int j = 0; j < 4; ++j) {
    int g = (j * 4 + w) * 64 + lane;
    int row = g >> 3, gi = g & 7;
    int gj = gi ^ (row & 7);
    int grow = m0 + row;
    if (grow >= n) grow = n - 1;
    agp[j] = x + (size_t)grow * DI + gj * 4;
    abase[j] = (j * 4 + w) * 256;  // float offset of op base (lane 0)
  }
  // B staging: 2 ops/wave; granule g = (j*4+w)*64 + lane; c = g>>2, gi = g&3
  // swizzle: gi ^ ((c>>1)&3) -> same-parity lanes spread over all 4 slots (2-way, free)
  const _Float16* bgp[2];
  int bbase[2];
#pragma unroll
  for (int j = 0; j < 2; ++j) {
    int g = (j * 4 + w) * 64 + lane;
    int c = g >> 2, gi = g & 3;
    int gj = gi ^ ((c >> 1) & 3);
    bgp[j] = w16 + (size_t)c * DI + gj * 8;
    bbase[j] = (j * 4 + w) * 512;  // half offset of op base (lane 0)
  }

  f32x4 acc[2][8];
#pragma unroll
  for (int mi = 0; mi < 2; ++mi)
#pragma unroll
    for (int ni = 0; ni < 8; ++ni) acc[mi][ni] = (f32x4){0.f, 0.f, 0.f, 0.f};

  int r0l = w * 32 + lm, r1l = r0l + 16;
  int sw = lm & 7;                        // A-read swizzle ((r&7) same for r0l/r1l)
  int bsw = (lk ^ ((lm >> 1) & 3)) << 3;  // B-read swizzle (halfs)

  auto compute_tile = [&](const float* ab, const _Float16* bb) {
    f32x4 v0a = *(const f32x4*)(ab + r0l * 32 + (((lk * 2 + 0) ^ sw) << 2));
    f32x4 v0b = *(const f32x4*)(ab + r0l * 32 + (((lk * 2 + 1) ^ sw) << 2));
    f32x4 v1a = *(const f32x4*)(ab + r1l * 32 + (((lk * 2 + 0) ^ sw) << 2));
    f32x4 v1b = *(const f32x4*)(ab + r1l * 32 + (((lk * 2 + 1) ^ sw) << 2));
    half8 a0, a1;
#pragma unroll
    for (int j = 0; j < 4; ++j) {
      a0[j] = (_Float16)v0a[j]; a0[4 + j] = (_Float16)v0b[j];
      a1[j] = (_Float16)v1a[j]; a1[4 + j] = (_Float16)v1b[j];
    }
#pragma unroll
    for (int ni = 0; ni < 8; ++ni) {
      half8 b = *(const half8*)(bb + ni * 512 + lm * 32 + bsw);
      acc[0][ni] = __builtin_amdgcn_mfma_f32_16x16x32_f16(a0, b, acc[0][ni], 0, 0, 0);
      acc[1][ni] = __builtin_amdgcn_mfma_f32_16x16x32_f16(a1, b, acc[1][ni], 0, 0, 0);
    }
  };

  // prologue: stage tile 0
#pragma unroll
  for (int j = 0; j < 4; ++j) async_copy16(agp[j], &aS[0][abase[j]]);
#pragma unroll
  for (int j = 0; j < 2; ++j) async_copy16(bgp[j], &bS[0][bbase[j]]);

  for (int ts = 0; ts < NT - 1; ++ts) {
    int cur = ts & 1;
    int kc = (ts + 1) * BK;
#pragma unroll
    for (int j = 0; j < 4; ++j) async_copy16(agp[j] + kc, &aS[cur ^ 1][abase[j]]);
#pragma unroll
    for (int j = 0; j < 2; ++j) async_copy16(bgp[j] + kc, &bS[cur ^ 1][bbase[j]]);
    asm volatile("s_waitcnt vmcnt(6)" ::: "memory");  // tile ts landed (6 newer in flight)
    raw_barrier();  // all waves' portions in LDS; NO vmcnt(0) drain here
    compute_tile(aS[cur], bS[cur]);
    raw_barrier();  // all waves done reading buf[cur] before iter ts+1 overwrites it
  }
  // epilogue: last tile
  asm volatile("s_waitcnt vmcnt(0)" ::: "memory");
  raw_barrier();
  compute_tile(aS[(NT - 1) & 1], bS[(NT - 1) & 1]);

  // C/D: col = ni*16 + lm, row = m0 + w*32 + mi*16 + lk*4 + j
#pragma unroll
  for (int mi = 0; mi < 2; ++mi)
#pragma unroll
    for (int ni = 0; ni < 8; ++ni) {
      int col = ni * 16 + lm;
#pragma unroll
      for (int j = 0; j < 4; ++j) {
        int row = m0 + w * 32 + mi * 16 + lk * 4 + j;
        if (row < n) {
          float v = acc[mi][ni][j];
          if (col < 64) p[(size_t)row * 64 + col] = (_Float16)v;
          else q[(size_t)row * 64 + (col - 64)] = (_Float16)(v + bias[col - 64]);
        }
      }
    }
}

// ---------------- fused aggregate(+relu) -> gemm for layers 2-4 ----------------
template <int DIR, int DIP, int PSI, int NC, int NCR, int DO, int PSO>
__global__ __launch_bounds__(256) void fused_agg_gemm_kernel(
    const _Float16* __restrict__ pin, const _Float16* __restrict__ qin,
    const int* __restrict__ off, const int* __restrict__ csr, const float* __restrict__ invd,
    const _Float16* __restrict__ w16, const float* __restrict__ bias,
    _Float16* __restrict__ pout, _Float16* __restrict__ qout, int n) {
  constexpr int SP = DIP + 8;
  constexpr int C8 = DIR / 8;
  constexpr int CT = C8 / 2;
  constexpr int NF = NC / 16;
  __shared__ _Float16 hs[128 * SP];
  int t = threadIdx.x;
  int node_l = t >> 1, half = t & 1;
  int node = blockIdx.x * 128 + node_l;

  if (node < n) {
    int e0 = off[node], e1 = off[node + 1];
    const half8* p8 = (const half8*)pin;
    float s[CT][8];
#pragma unroll
    for (int c = 0; c < CT; ++c)
#pragma unroll
      for (int j = 0; j < 8; ++j) s[c][j] = 0.f;
    for (int e = e0; e < e1; ++e) {
      int src = csr[e];
#pragma unroll
      for (int c = 0; c < CT; ++c) {
        half8 v = p8[(size_t)src * PSI + half * CT + c];
#pragma unroll
        for (int j = 0; j < 8; ++j) s[c][j] += (float)v[j];
      }
    }
    float id = invd[node];
#pragma unroll
    for (int c = 0; c < CT; ++c) {
      half8 qv = ((const half8*)qin)[(size_t)node * PSI + half * CT + c];
      half8 o;
#pragma unroll
      for (int j = 0; j < 8; ++j) o[j] = (_Float16)fmaxf(s[c][j] * id + (float)qv[j], 0.f);
      *(half8*)(hs + node_l * SP + (half * CT + c) * 8) = o;
    }
    if (DIP > DIR) {
      half8 z = {};
      *(half8*)(hs + node_l * SP + (C8 + half) * 8) = z;
    }
  }
  __syncthreads();

  int lane = t & 63, w = t >> 6;
  int lm = lane & 15, lk = lane >> 4;
  int r0l = w * 32 + lm, r1l = r0l + 16;
  const _Float16* wp = w16 + (size_t)lm * DIP + lk * 8;
  f32x4 acc[2][NF];
#pragma unroll
  for (int mi = 0; mi < 2; ++mi)
#pragma unroll
    for (int ni = 0; ni < NF; ++ni) acc[mi][ni] = (f32x4){0.f, 0.f, 0.f, 0.f};
#pragma unroll
  for (int kc = 0; kc < DIP; kc += 32) {
    half8 a0 = *(const half8*)(hs + r0l * SP + kc + lk * 8);
    half8 a1 = *(const half8*)(hs + r1l * SP + kc + lk * 8);
#pragma unroll
    for (int ni = 0; ni < NF; ++ni) {
      half8 b = *(const half8*)(wp + (size_t)ni * 16 * DIP + kc);
      acc[0][ni] = __builtin_amdgcn_mfma_f32_16x16x32_f16(a0, b, acc[0][ni], 0, 0, 0);
      acc[1][ni] = __builtin_amdgcn_mfma_f32_16x16x32_f16(a1, b, acc[1][ni], 0, 0, 0);
    }
  }
#pragma unroll
  for (int mi = 0; mi < 2; ++mi)
#pragma unroll
    for (int ni = 0; ni < NF; ++ni) {
      int col = ni * 16 + lm;
      if (col >= NCR) continue;
#pragma unroll
      for (int j = 0; j < 4; ++j) {
        int row = blockIdx.x * 128 + w * 32 + mi * 16 + lk * 4 + j;
        if (row < n) {
          float v = acc[mi][ni][j];
          if (col < DO) pout[(size_t)row * PSO + col] = (_Float16)v;
          else qout[(size_t)row * PSO + (col - DO)] = (_Float16)(v + bias[col - DO]);
        }
      }
    }
}

// final aggregation: p,q fp16 [n][8] (cols 0-4 valid), out fp32 [n][5]
__global__ __launch_bounds__(256) void aggregate_last_kernel(
    const _Float16* __restrict__ p, const _Float16* __restrict__ q,
    const int* __restrict__ off, const int* __restrict__ csr,
    const float* __restrict__ invd, float* __restrict__ out, int n) {
  int t = blockIdx.x * 256 + threadIdx.x;
  int node = t >> 3;
  int c = t & 7;
  if (node >= n || c >= 5) return;
  int e0 = off[node], e1 = off[node + 1];
  float s = 0.f;
  for (int e = e0; e < e1; ++e) s += (float)p[(size_t)csr[e] * 8 + c];
  out[(size_t)node * 5 + c] = s * invd[node] + (float)q[(size_t)node * 8 + c];
}

// ---------------- launch ----------------
extern "C" void kernel_launch(void* const* d_in, const int* in_sizes, int n_in,
                              void* d_out, int out_size, void* d_ws, size_t ws_size,
                              hipStream_t stream) {
  const float* x = (const float*)d_in[0];
  const int* ei = (const int*)d_in[1];
  const int E = in_sizes[1] / 2;
  const int* esrc = ei;
  const int* edst = ei + E;
  const float* W1l = (const float*)d_in[3];
  const float* W1r = (const float*)d_in[4];
  const float* b1 = (const float*)d_in[5];
  const float* W2l = (const float*)d_in[6];
  const float* W2r = (const float*)d_in[7];
  const float* b2 = (const float*)d_in[8];
  const float* W3l = (const float*)d_in[9];
  const float* W3r = (const float*)d_in[10];
  const float* b3 = (const float*)d_in[11];
  const float* W4l = (const float*)d_in[12];
  const float* W4r = (const float*)d_in[13];
  const float* b4 = (const float*)d_in[14];
  const int N = in_sizes[0] / 768;
  float* out = (float*)d_out;
  (void)n_in; (void)out_size; (void)ws_size;

  char* base = (char*)d_ws;
  size_t o = 0;
  auto alloc = [&](size_t bytes) -> void* {
    void* ptr = base + o;
    o = (o + bytes + 255) & ~(size_t)255;
    return ptr;
  };
  int* cnt = (int*)alloc((size_t)2 * N * 4);  // cnt + cur contiguous
  int* cur = cnt + N;
  int* off = (int*)alloc((size_t)(N + 1) * 4);
  int* bsum = (int*)alloc(1024);
  int* csr = (int*)alloc((size_t)E * 4);
  float* invd = (float*)alloc((size_t)N * 4);
  _Float16* w1 = (_Float16*)alloc((size_t)128 * 768 * 2);
  _Float16* w2 = (_Float16*)alloc((size_t)64 * 64 * 2);
  _Float16* w3 = (_Float16*)alloc((size_t)32 * 32 * 2);
  _Float16* w4 = (_Float16*)alloc((size_t)16 * 32 * 2);
  _Float16* P1 = (_Float16*)alloc((size_t)N * 64 * 2);
  _Float16* Q1 = (_Float16*)alloc((size_t)N * 64 * 2);
  _Float16* P2 = (_Float16*)alloc((size_t)N * 32 * 2);
  _Float16* Q2 = (_Float16*)alloc((size_t)N * 32 * 2);
  _Float16* P3 = (_Float16*)alloc((size_t)N * 16 * 2);
  _Float16* Q3 = (_Float16*)alloc((size_t)N * 16 * 2);
  _Float16* P4 = (_Float16*)alloc((size_t)N * 8 * 2);
  _Float16* Q4 = (_Float16*)alloc((size_t)N * 8 * 2);

  const int n4 = (2 * N + 3) / 4;
  zero_kernel<<<(n4 + 255) / 256, 256, 0, stream>>>((int4*)cnt, n4);
  prep_all_kernel<<<(98304 + 4096 + 1024 + 512 + 255) / 256, 256, 0, stream>>>(
      W1l, W1r, W2l, W2r, W3l, W3r, W4l, W4r, w1, w2, w3, w4);

  deg_kernel<<<(E + 255) / 256, 256, 0, stream>>>(edst, cnt, E);
  const int nb = (N + 1 + 1023) / 1024;
  scan1_kernel<<<nb, 256, 0, stream>>>(cnt, off, bsum, invd, N);
  scan2_kernel<<<1, 128, 0, stream>>>(bsum, nb);
  scan3_kernel<<<(N + 1 + 255) / 256, 256, 0, stream>>>(off, bsum, N + 1);
  sortfill_kernel<<<(E + 255) / 256, 256, 0, stream>>>(esrc, edst, off, cur, csr, E);

  const int gb = (N + 127) / 128;
  // Layer 1: 768 -> 64 (A+B LDS-staged MFMA, counted-vmcnt pipeline, raw barriers)
  gemm1_kernel<<<gb, 256, 0, stream>>>(x, w1, b1, P1, Q1, N);
  // Layers 2-4 fused with preceding aggregation
  fused_agg_gemm_kernel<64, 64, 8, 64, 64, 32, 32>
      <<<gb, 256, 0, stream>>>(P1, Q1, off, csr, invd, w2, b2, P2, Q2, N);
  fused_agg_gemm_kernel<32, 32, 4, 32, 32, 16, 16>
      <<<gb, 256, 0, stream>>>(P2, Q2, off, csr, invd, w3, b3, P3, Q3, N);
  fused_agg_gemm_kernel<16, 32, 2, 16, 10, 5, 8>
      <<<gb, 256, 0, stream>>>(P3, Q3, off, csr, invd, w4, b4, P4, Q4, N);
  aggregate_last_kernel<<<(N * 8 + 255) / 256, 256, 0, stream>>>(P4, Q4, off, csr, invd, out, N);
}